// Round 10
// baseline (208.328 us; speedup 1.0000x reference)
//
#include <hip/hip_runtime.h>

// ContrastiveLoss on MI355X (gfx950) — round 14
// loss = (1/n) [ sum_i P_i*ln(zraw_i) - 10*(sum_c ||S_c||^2 - n) ]
//   zraw_i = sum_{j != i} exp2(K2E*dot_ij)
// R14: R13's wave-stagger REVERTED (it broke the affine B-address walk and
// the cross-wave lag-4 L1 reuse: +9us). Kept from R13: SQK pre-scale
// (exp2-direct, no fmaf) + packed f32x4 epilogue. New: final_kernel fused
// into zsum via last-block pattern (threadfence + counter in zeroed cnt
// slab); prep zeroes the z slab so memset shrinks to 512 B.

#define N 8192
#define D 128
#define NCLS 100
#define NTILE 512          // N/16 tiles
#define RLCAP 256          // rowlist slots per class (~82+-9 expected)
#define MWIN 8             // m-values per window
#define YGRID 32           // m-windows: covers m = 1..256 (+extras 257..259)
#define XGRID 36           // 32 zsum i-blocks + 4 cols of classsum blocks
#define NBLK (XGRID * YGRID)
#define LDS_TILES 20       // rel = w*4 (<=12) + (m-m_lo) (<=7)
#define SQK 3.79828256f    // sqrt(10*log2(e)); SQK^2 = K2E to ~2e-8 rel
#define LN2 0.69314718055994530942f

typedef __bf16 bf16x8 __attribute__((ext_vector_type(8)));
typedef float f32x4 __attribute__((ext_vector_type(4)));

// ws layout (bytes)
#define EBF_OFF  0x000000u  // bf16 E*SQK fragment-major: 2 MB
#define ENORM_OFF 0x200000u // fp32 normalized E row-major (UNSCALED): 4 MB
#define CNT_OFF  0x600000u  // class counts + block counter: 512 B (zeroed)
#define Z_OFF    0x600200u  // z per row: 32 KB (zeroed by prep)
#define RL_OFF   0x608200u  // rowlist: 100*256*4 = 100 KB (gated by cnt)
#define S_OFF    0x621200u  // S_c: 100*128*4 = 50 KB (fully written)
#define ZERO_SZ  512u
#define CTR_SLOT 120        // counter index within cnt slab (ints 0..127)

__device__ __forceinline__ unsigned short f32_to_bf16_rne(float f) {
    unsigned int u = __float_as_uint(f);
    u += 0x7fffu + ((u >> 16) & 1u);
    return (unsigned short)(u >> 16);
}

// Fragment-major layout of E (harness-verified):
//   row r: grp=r>>4, col=r&15 ; element k: c=k>>5, q=(k>>3)&3, jj=k&7
//   byte = grp*4096 + c*1024 + q*256 + col*16 + jj*2
// float4 lane mapping: lane li in [0,32) holds k=4li..4li+3 ->
//   c=li>>3, q=(li>>1)&3, byte base + (li&1)*8, one 8B store.

// Kernel 1: normalize rows -> fragment-major bf16 E*SQK + fp32 enorm;
// class histogram doubles as rowlist slot allocator; zeroes the z slab.
__global__ __launch_bounds__(256) void prep_kernel(
        const float* __restrict__ emb, const int* __restrict__ labels,
        unsigned char* __restrict__ ebf, int* __restrict__ cnt,
        float* __restrict__ enorm, int* __restrict__ rowlist,
        float* __restrict__ z) {
    const int w    = threadIdx.x >> 6;
    const int lane = threadIdx.x & 63;
    const int h    = lane >> 5;
    const int li   = lane & 31;
    const int row  = blockIdx.x * 8 + w * 2 + h;

    if (threadIdx.x < 8) z[blockIdx.x * 8 + threadIdx.x] = 0.0f;

    const float4 v = *(const float4*)(emb + (size_t)row * D + li * 4);
    float ss = v.x * v.x + v.y * v.y + v.z * v.z + v.w * v.w;
    #pragma unroll
    for (int off = 16; off; off >>= 1) ss += __shfl_xor(ss, off);   // within half
    const float inv = 1.0f / fmaxf(sqrtf(ss), 1e-12f);
    const float e0 = v.x * inv, e1 = v.y * inv, e2 = v.z * inv, e3 = v.w * inv;

    const int grp = row >> 4, col = row & 15;
    const int c = li >> 3, q = (li >> 1) & 3, jh = li & 1;
    uint2 packed;
    packed.x = (unsigned)f32_to_bf16_rne(e0 * SQK) | ((unsigned)f32_to_bf16_rne(e1 * SQK) << 16);
    packed.y = (unsigned)f32_to_bf16_rne(e2 * SQK) | ((unsigned)f32_to_bf16_rne(e3 * SQK) << 16);
    *(uint2*)(ebf + grp * 4096 + c * 1024 + q * 256 + col * 16 + jh * 8) = packed;

    *(float4*)(enorm + (size_t)row * D + li * 4) = make_float4(e0, e1, e2, e3);

    if (li == 0) {
        const int lab = labels[row];
        int slot = atomicAdd(&cnt[lab], 1);
        slot = slot < RLCAP ? slot : RLCAP - 1;   // defensive
        rowlist[lab * RLCAP + slot] = row;
    }
}

// Kernel 2: zsum (blocks x<32) + classsum (blocks x>=32) + fused epilogue
// (last block computes the loss). zsum: circulant symmetry — wave owns 4
// consecutive i-tiles; window y handles m in [8y+1, 8y+8] (+extras);
// monotone m-walk (affine B addresses, cross-wave lag-4 L1 reuse).
__global__ __launch_bounds__(256) void zsum_kernel(
        const unsigned char* __restrict__ ebf, float* __restrict__ z,
        const float* __restrict__ enorm, int* __restrict__ cnt,
        const int* __restrict__ rowlist, float* __restrict__ S,
        const int* __restrict__ labels, float* __restrict__ out) {
    __shared__ float zcol[LDS_TILES * 16];
    __shared__ float part[4];
    __shared__ unsigned lastflag;
    const int t = threadIdx.x;

    if (blockIdx.x >= 32) {
        // ---- classsum path: exact fp32 per-class sums via rowlist gather ----
        const int eidx = (blockIdx.x - 32) * YGRID + blockIdx.y;
        if (eidx < NCLS && t < 128) {
            const int d = t;
            const int n = cnt[eidx] < RLCAP ? cnt[eidx] : RLCAP;
            const int* rl = rowlist + eidx * RLCAP;
            float acc = 0.0f;
            int idx = 0;
            for (; idx + 4 <= n; idx += 4) {
                const int r0 = rl[idx], r1 = rl[idx + 1], r2 = rl[idx + 2], r3 = rl[idx + 3];
                acc += enorm[(size_t)r0 * D + d] + enorm[(size_t)r1 * D + d]
                     + enorm[(size_t)r2 * D + d] + enorm[(size_t)r3 * D + d];
            }
            for (; idx < n; ++idx)
                acc += enorm[(size_t)rl[idx] * D + d];
            S[eidx * D + d] = acc;
        }
    } else {
        // ---- zsum path ----
        const int w    = t >> 6;
        const int lane = t & 63;
        const int q    = lane >> 4;
        const int col  = lane & 15;
        const int bi   = blockIdx.x;                 // 0..31  i-block
        const int y    = blockIdx.y;                 // 0..31  m-window
        const int ti0  = bi * 16 + w * 4;            // wave's first i-tile
        const int m_lo = y * MWIN + 1;
        const bool lowhalf = (bi < 16);

        for (int e = t; e < LDS_TILES * 16; e += 256) zcol[e] = 0.0f;

        // A fragments: 4 i-tiles x 4 K-chunks, coalesced 1KB loads
        bf16x8 a[4][4];
        #pragma unroll
        for (int g = 0; g < 4; ++g) {
            const unsigned char* ag = ebf + (size_t)(ti0 + g) * 4096 + lane * 16;
            #pragma unroll
            for (int c = 0; c < 4; ++c) a[g][c] = *(const bf16x8*)(ag + c * 1024);
        }

        f32x4 zacc4[4] = {{0.f,0.f,0.f,0.f},{0.f,0.f,0.f,0.f},
                          {0.f,0.f,0.f,0.f},{0.f,0.f,0.f,0.f}};

        __syncthreads();   // zcol zeroed

        // diagonal tiles: window 0 only; full tile, self excluded, row-sums
        if (y == 0) {
            #pragma unroll
            for (int g = 0; g < 4; ++g) {
                const unsigned char* bg = ebf + (size_t)(ti0 + g) * 4096 + lane * 16;
                bf16x8 bd[4];
                #pragma unroll
                for (int c = 0; c < 4; ++c) bd[c] = *(const bf16x8*)(bg + c * 1024);
                f32x4 acc = {0.f, 0.f, 0.f, 0.f};
                #pragma unroll
                for (int c = 0; c < 4; ++c)
                    acc = __builtin_amdgcn_mfma_f32_16x16x32_bf16(a[g][c], bd[c], acc, 0, 0, 0);
                #pragma unroll
                for (int r = 0; r < 4; ++r)
                    zacc4[g][r] += (col == q * 4 + r) ? 0.0f
                        : __builtin_amdgcn_exp2f(acc[r]);
            }
        }

        const int ns = MWIN + ((y == 29 || y == 30 || (y == 31 && lowhalf)) ? 1 : 0);
        const int m_x = 228 + y;

        // prologue: load B tile for s=0
        bf16x8 bc[4];
        {
            const int tj = (ti0 + m_lo) & (NTILE - 1);
            const unsigned char* bg = ebf + (size_t)tj * 4096 + lane * 16;
            #pragma unroll
            for (int c = 0; c < 4; ++c) bc[c] = *(const bf16x8*)(bg + c * 1024);
        }

        #pragma unroll 2
        for (int s = 0; s < ns; ++s) {
            const int m = (s < MWIN) ? (m_lo + s) : m_x;

            const int sn = (s + 1 < ns) ? s + 1 : s;
            const int mn = (sn < MWIN) ? (m_lo + sn) : m_x;
            bf16x8 bn[4];
            {
                const int tjn = (ti0 + mn) & (NTILE - 1);
                const unsigned char* bg = ebf + (size_t)tjn * 4096 + lane * 16;
                #pragma unroll
                for (int c = 0; c < 4; ++c) bn[c] = *(const bf16x8*)(bg + c * 1024);
            }

            f32x4 ct = {0.f, 0.f, 0.f, 0.f};
            #pragma unroll
            for (int g = 0; g < 4; ++g) {
                const int d = m - g;
                const bool act = (d >= 1 && d <= 255) || (d == 256 && lowhalf);
                if (act) {
                    f32x4 acc = {0.f, 0.f, 0.f, 0.f};
                    __builtin_amdgcn_s_setprio(1);
                    #pragma unroll
                    for (int c = 0; c < 4; ++c)
                        acc = __builtin_amdgcn_mfma_f32_16x16x32_bf16(a[g][c], bc[c], acc, 0, 0, 0);
                    __builtin_amdgcn_s_setprio(0);
                    f32x4 p;
                    #pragma unroll
                    for (int r = 0; r < 4; ++r)
                        p[r] = __builtin_amdgcn_exp2f(acc[r]);
                    zacc4[g] += p;
                    ct += p;
                }
            }

            float ctot = (ct[0] + ct[1]) + (ct[2] + ct[3]);
            ctot += __shfl_xor(ctot, 16);
            ctot += __shfl_xor(ctot, 32);
            if (q == 0 && ctot != 0.0f) {
                if (s < MWIN) {
                    const int rel = w * 4 + (m - m_lo);          // 0..19
                    atomicAdd(&zcol[rel * 16 + col], ctot);
                } else {
                    const int tj = (ti0 + m) & (NTILE - 1);
                    atomicAdd(&z[tj * 16 + col], ctot);
                }
            }

            #pragma unroll
            for (int c = 0; c < 4; ++c) bc[c] = bn[c];
        }

        // i-side: per-row reduce across the 16 cols of each quad
        #pragma unroll
        for (int g = 0; g < 4; ++g)
            #pragma unroll
            for (int r = 0; r < 4; ++r) {
                float zv = zacc4[g][r];
                zv += __shfl_xor(zv, 1);
                zv += __shfl_xor(zv, 2);
                zv += __shfl_xor(zv, 4);
                zv += __shfl_xor(zv, 8);
                if (col == 0)
                    atomicAdd(&z[(ti0 + g) * 16 + q * 4 + r], zv);
            }

        // j-side: flush LDS col-partials once
        __syncthreads();
        for (int e = t; e < LDS_TILES * 16; e += 256) {
            const float v = zcol[e];
            if (v != 0.0f) {
                const int tj = (bi * 16 + m_lo + (e >> 4)) & (NTILE - 1);
                atomicAdd(&z[tj * 16 + (e & 15)], v);
            }
        }
    }

    // ---- fused epilogue: last block computes the loss ----
    __threadfence();           // release this block's S stores / z atomics
    __syncthreads();
    if (t == 0) lastflag = atomicAdd((unsigned*)&cnt[CTR_SLOT], 1u);
    __syncthreads();
    if (lastflag == NBLK - 1) {
        __threadfence();       // acquire: all other blocks' writes visible
        float acc = 0.0f;
        #pragma unroll 4
        for (int k = 0; k < N / 256; ++k) {
            const int row = k * 256 + t;
            const int P = cnt[labels[row]] - 1;
            if (P > 0)
                acc += (float)P * (LN2 * __builtin_amdgcn_logf(z[row]));
        }
        for (int k = t; k < NCLS * D; k += 256) {
            const float sv = S[k];
            acc -= 10.0f * sv * sv;
        }
        #pragma unroll
        for (int off = 32; off; off >>= 1) acc += __shfl_xor(acc, off);
        if ((t & 63) == 0) part[t >> 6] = acc;
        __syncthreads();
        if (t == 0)
            out[0] = ((part[0] + part[1]) + (part[2] + part[3]) + 10.0f * (float)N)
                     * (1.0f / (float)N);
    }
}

extern "C" void kernel_launch(void* const* d_in, const int* in_sizes, int n_in,
                              void* d_out, int out_size, void* d_ws, size_t ws_size,
                              hipStream_t stream) {
    const float* emb  = (const float*)d_in[0];
    const int* labels = (const int*)d_in[1];
    float* out        = (float*)d_out;
    char* ws          = (char*)d_ws;

    unsigned char* ebf = (unsigned char*)(ws + EBF_OFF);
    float* enorm       = (float*)(ws + ENORM_OFF);
    int*   cnt         = (int*)(ws + CNT_OFF);
    float* z           = (float*)(ws + Z_OFF);
    int*   rowlist     = (int*)(ws + RL_OFF);
    float* S           = (float*)(ws + S_OFF);

    hipMemsetAsync(ws + CNT_OFF, 0, ZERO_SZ, stream);

    prep_kernel<<<N / 8, 256, 0, stream>>>(emb, labels, ebf, cnt, enorm, rowlist, z);
    zsum_kernel<<<dim3(XGRID, YGRID), 256, 0, stream>>>(ebf, z, enorm, cnt, rowlist, S,
                                                        labels, out);
}

// Round 11
// 125.037 us; speedup vs baseline: 1.6661x; 1.6661x over previous
//
#include <hip/hip_runtime.h>

// ContrastiveLoss on MI355X (gfx950) — round 15
// loss = (1/n) [ sum_i P_i*ln(zraw_i) - 10*(sum_c ||S_c||^2 - n) ]
//   zraw_i = sum_{j != i} exp2(K2E*dot_ij)
// R15: R14's fused last-block epilogue REVERTED — its per-block device-scope
// __threadfence() (buffer_wbl2: L2 writeback, XCDs non-coherent) serialized
// 1152 blocks -> zsum 131us @ MfmaUtil 2.5%. Separate final_kernel restores
// the free device-wide visibility of a dispatch boundary. Structure = R12
// (115.9us) + R13's strictly-work-removing items: SQK pre-scale (exp2
// direct, no fmaf) and packed f32x4 epilogue. Monotone m-walk (R13's
// stagger cost +9us: broke affine B-addressing + cross-wave L1 reuse).

#define N 8192
#define D 128
#define NCLS 100
#define NTILE 512          // N/16 tiles
#define RLCAP 256          // rowlist slots per class (~82+-9 expected)
#define MWIN 8             // m-values per window
#define YGRID 32           // m-windows: covers m = 1..256 (+extras 257..259)
#define XGRID 36           // 32 zsum i-blocks + 4 cols of classsum blocks
#define LDS_TILES 20       // rel = w*4 (<=12) + (m-m_lo) (<=7)
#define SQK 3.79828256f    // sqrt(10*log2(e)); SQK^2 = K2E to ~2e-8 rel
#define LN2 0.69314718055994530942f

typedef __bf16 bf16x8 __attribute__((ext_vector_type(8)));
typedef float f32x4 __attribute__((ext_vector_type(4)));

// ws layout (bytes)
#define EBF_OFF  0x000000u  // bf16 E*SQK fragment-major: 2 MB
#define ENORM_OFF 0x200000u // fp32 normalized E row-major (UNSCALED): 4 MB
#define CNT_OFF  0x600000u  // class counts: 512 B (zeroed)
#define Z_OFF    0x600200u  // z per row: 32 KB (zeroed by prep)
#define RL_OFF   0x608200u  // rowlist: 100*256*4 = 100 KB (gated by cnt)
#define S_OFF    0x621200u  // S_c: 100*128*4 = 50 KB (fully written)
#define ZERO_SZ  512u

__device__ __forceinline__ unsigned short f32_to_bf16_rne(float f) {
    unsigned int u = __float_as_uint(f);
    u += 0x7fffu + ((u >> 16) & 1u);
    return (unsigned short)(u >> 16);
}

// Fragment-major layout of E (harness-verified):
//   row r: grp=r>>4, col=r&15 ; element k: c=k>>5, q=(k>>3)&3, jj=k&7
//   byte = grp*4096 + c*1024 + q*256 + col*16 + jj*2
// float4 lane mapping: lane li in [0,32) holds k=4li..4li+3 ->
//   c=li>>3, q=(li>>1)&3, byte base + (li&1)*8, one 8B store.

// Kernel 1: normalize rows -> fragment-major bf16 E*SQK + fp32 enorm;
// class histogram doubles as rowlist slot allocator; zeroes the z slab.
__global__ __launch_bounds__(256) void prep_kernel(
        const float* __restrict__ emb, const int* __restrict__ labels,
        unsigned char* __restrict__ ebf, int* __restrict__ cnt,
        float* __restrict__ enorm, int* __restrict__ rowlist,
        float* __restrict__ z) {
    const int w    = threadIdx.x >> 6;
    const int lane = threadIdx.x & 63;
    const int h    = lane >> 5;
    const int li   = lane & 31;
    const int row  = blockIdx.x * 8 + w * 2 + h;

    if (threadIdx.x < 8) z[blockIdx.x * 8 + threadIdx.x] = 0.0f;

    const float4 v = *(const float4*)(emb + (size_t)row * D + li * 4);
    float ss = v.x * v.x + v.y * v.y + v.z * v.z + v.w * v.w;
    #pragma unroll
    for (int off = 16; off; off >>= 1) ss += __shfl_xor(ss, off);   // within half
    const float inv = 1.0f / fmaxf(sqrtf(ss), 1e-12f);
    const float e0 = v.x * inv, e1 = v.y * inv, e2 = v.z * inv, e3 = v.w * inv;

    const int grp = row >> 4, col = row & 15;
    const int c = li >> 3, q = (li >> 1) & 3, jh = li & 1;
    uint2 packed;
    packed.x = (unsigned)f32_to_bf16_rne(e0 * SQK) | ((unsigned)f32_to_bf16_rne(e1 * SQK) << 16);
    packed.y = (unsigned)f32_to_bf16_rne(e2 * SQK) | ((unsigned)f32_to_bf16_rne(e3 * SQK) << 16);
    *(uint2*)(ebf + grp * 4096 + c * 1024 + q * 256 + col * 16 + jh * 8) = packed;

    *(float4*)(enorm + (size_t)row * D + li * 4) = make_float4(e0, e1, e2, e3);

    if (li == 0) {
        const int lab = labels[row];
        int slot = atomicAdd(&cnt[lab], 1);
        slot = slot < RLCAP ? slot : RLCAP - 1;   // defensive
        rowlist[lab * RLCAP + slot] = row;
    }
}

// Kernel 2: zsum (blocks x<32) + classsum (blocks x>=32, 1 class each).
// zsum: circulant symmetry — wave owns 4 consecutive i-tiles; window y
// handles m in [8y+1, 8y+8] (+1 extra for y in {29,30,31}); monotone
// m-walk. Group g active iff d=m-g in [1,255], or d==256 for low-half
// blocks. Diagonal tiles: window 0, row-sums with self-exclusion.
// Off-diag credit BOTH sides: rows in registers, cols via LDS partials.
__global__ __launch_bounds__(256) void zsum_kernel(
        const unsigned char* __restrict__ ebf, float* __restrict__ z,
        const float* __restrict__ enorm, const int* __restrict__ cnt,
        const int* __restrict__ rowlist, float* __restrict__ S) {
    const int t = threadIdx.x;

    if (blockIdx.x >= 32) {
        // ---- classsum path: exact fp32 per-class sums via rowlist gather ----
        const int eidx = (blockIdx.x - 32) * YGRID + blockIdx.y;
        if (eidx >= NCLS || t >= 128) return;
        const int d = t;
        const int n = cnt[eidx] < RLCAP ? cnt[eidx] : RLCAP;
        const int* rl = rowlist + eidx * RLCAP;
        float acc = 0.0f;
        int idx = 0;
        for (; idx + 4 <= n; idx += 4) {
            const int r0 = rl[idx], r1 = rl[idx + 1], r2 = rl[idx + 2], r3 = rl[idx + 3];
            acc += enorm[(size_t)r0 * D + d] + enorm[(size_t)r1 * D + d]
                 + enorm[(size_t)r2 * D + d] + enorm[(size_t)r3 * D + d];
        }
        for (; idx < n; ++idx)
            acc += enorm[(size_t)rl[idx] * D + d];
        S[eidx * D + d] = acc;
        return;
    }

    // ---- zsum path ----
    __shared__ float zcol[LDS_TILES * 16];
    const int w    = t >> 6;
    const int lane = t & 63;
    const int q    = lane >> 4;
    const int col  = lane & 15;
    const int bi   = blockIdx.x;                 // 0..31  i-block
    const int y    = blockIdx.y;                 // 0..31  m-window
    const int ti0  = bi * 16 + w * 4;            // wave's first i-tile
    const int m_lo = y * MWIN + 1;
    const bool lowhalf = (bi < 16);

    for (int e = t; e < LDS_TILES * 16; e += 256) zcol[e] = 0.0f;

    // A fragments: 4 i-tiles x 4 K-chunks, coalesced 1KB loads
    bf16x8 a[4][4];
    #pragma unroll
    for (int g = 0; g < 4; ++g) {
        const unsigned char* ag = ebf + (size_t)(ti0 + g) * 4096 + lane * 16;
        #pragma unroll
        for (int c = 0; c < 4; ++c) a[g][c] = *(const bf16x8*)(ag + c * 1024);
    }

    f32x4 zacc4[4] = {{0.f,0.f,0.f,0.f},{0.f,0.f,0.f,0.f},
                      {0.f,0.f,0.f,0.f},{0.f,0.f,0.f,0.f}};

    __syncthreads();   // zcol zeroed

    // diagonal tiles: window 0 only; full tile, self excluded, row-sums only
    if (y == 0) {
        #pragma unroll
        for (int g = 0; g < 4; ++g) {
            const unsigned char* bg = ebf + (size_t)(ti0 + g) * 4096 + lane * 16;
            bf16x8 bd[4];
            #pragma unroll
            for (int c = 0; c < 4; ++c) bd[c] = *(const bf16x8*)(bg + c * 1024);
            f32x4 acc = {0.f, 0.f, 0.f, 0.f};
            #pragma unroll
            for (int c = 0; c < 4; ++c)
                acc = __builtin_amdgcn_mfma_f32_16x16x32_bf16(a[g][c], bd[c], acc, 0, 0, 0);
            #pragma unroll
            for (int r = 0; r < 4; ++r)
                zacc4[g][r] += (col == q * 4 + r) ? 0.0f
                    : __builtin_amdgcn_exp2f(acc[r]);
        }
    }

    const int ns = MWIN + ((y == 29 || y == 30 || (y == 31 && lowhalf)) ? 1 : 0);
    const int m_x = 228 + y;

    // prologue: load B tile for s=0
    bf16x8 bc[4];
    {
        const int tj = (ti0 + m_lo) & (NTILE - 1);
        const unsigned char* bg = ebf + (size_t)tj * 4096 + lane * 16;
        #pragma unroll
        for (int c = 0; c < 4; ++c) bc[c] = *(const bf16x8*)(bg + c * 1024);
    }

    #pragma unroll 2
    for (int s = 0; s < ns; ++s) {
        const int m = (s < MWIN) ? (m_lo + s) : m_x;

        // prefetch next B tile (last iter reloads current — harmless)
        const int sn = (s + 1 < ns) ? s + 1 : s;
        const int mn = (sn < MWIN) ? (m_lo + sn) : m_x;
        bf16x8 bn[4];
        {
            const int tjn = (ti0 + mn) & (NTILE - 1);
            const unsigned char* bg = ebf + (size_t)tjn * 4096 + lane * 16;
            #pragma unroll
            for (int c = 0; c < 4; ++c) bn[c] = *(const bf16x8*)(bg + c * 1024);
        }

        f32x4 ct = {0.f, 0.f, 0.f, 0.f};
        #pragma unroll
        for (int g = 0; g < 4; ++g) {
            const int d = m - g;
            const bool act = (d >= 1 && d <= 255) || (d == 256 && lowhalf);
            if (act) {
                f32x4 acc = {0.f, 0.f, 0.f, 0.f};
                __builtin_amdgcn_s_setprio(1);
                #pragma unroll
                for (int c = 0; c < 4; ++c)
                    acc = __builtin_amdgcn_mfma_f32_16x16x32_bf16(a[g][c], bc[c], acc, 0, 0, 0);
                __builtin_amdgcn_s_setprio(0);
                f32x4 p;
                #pragma unroll
                for (int r = 0; r < 4; ++r)
                    p[r] = __builtin_amdgcn_exp2f(acc[r]);
                zacc4[g] += p;
                ct += p;
            }
        }

        // column sums -> j-side credit. Reduce 4->1, then across q.
        float ctot = (ct[0] + ct[1]) + (ct[2] + ct[3]);
        ctot += __shfl_xor(ctot, 16);
        ctot += __shfl_xor(ctot, 32);
        if (q == 0 && ctot != 0.0f) {
            if (s < MWIN) {
                const int rel = w * 4 + (m - m_lo);          // 0..19
                atomicAdd(&zcol[rel * 16 + col], ctot);
            } else {
                const int tj = (ti0 + m) & (NTILE - 1);
                atomicAdd(&z[tj * 16 + col], ctot);
            }
        }

        #pragma unroll
        for (int c = 0; c < 4; ++c) bc[c] = bn[c];
    }

    // i-side: per-row reduce across the 16 cols of each quad
    #pragma unroll
    for (int g = 0; g < 4; ++g)
        #pragma unroll
        for (int r = 0; r < 4; ++r) {
            float zv = zacc4[g][r];
            zv += __shfl_xor(zv, 1);
            zv += __shfl_xor(zv, 2);
            zv += __shfl_xor(zv, 4);
            zv += __shfl_xor(zv, 8);
            if (col == 0)
                atomicAdd(&z[(ti0 + g) * 16 + q * 4 + r], zv);
        }

    // j-side: flush LDS col-partials once
    __syncthreads();
    for (int e = t; e < LDS_TILES * 16; e += 256) {
        const float v = zcol[e];
        if (v != 0.0f) {
            const int tj = (bi * 16 + m_lo + (e >> 4)) & (NTILE - 1);
            atomicAdd(&z[tj * 16 + (e & 15)], v);
        }
    }
}

// Kernel 3: single-block epilogue.
// Row term: P*(10 + ln z_true) = P*ln(zraw) since z_true = e^-10 * zraw.
// loss = [ sum_i P_i*LN2*log2(zraw_i) - 10*sum_k S[k]^2 + 10*N ] / N
__global__ __launch_bounds__(1024) void final_kernel(
        const int* __restrict__ labels, const int* __restrict__ cnt,
        const float* __restrict__ z, const float* __restrict__ S,
        float* __restrict__ out) {
    __shared__ float part[16];
    const int tid = threadIdx.x;
    float acc = 0.0f;
    #pragma unroll
    for (int k = 0; k < N / 1024; ++k) {
        const int row = k * 1024 + tid;
        const int P = cnt[labels[row]] - 1;
        if (P > 0)
            acc += (float)P * (LN2 * __builtin_amdgcn_logf(z[row]));
    }
    #pragma unroll
    for (int k = 0; k < (NCLS * D + 1023) / 1024; ++k) {
        const int idx = k * 1024 + tid;
        if (idx < NCLS * D) {
            const float sv = S[idx];
            acc -= 10.0f * sv * sv;
        }
    }
    #pragma unroll
    for (int off = 32; off; off >>= 1) acc += __shfl_xor(acc, off);
    if ((tid & 63) == 0) part[tid >> 6] = acc;
    __syncthreads();
    if (tid == 0) {
        float tot = 0.0f;
        #pragma unroll
        for (int w = 0; w < 16; ++w) tot += part[w];
        out[0] = (tot + 10.0f * (float)N) * (1.0f / (float)N);
    }
}

extern "C" void kernel_launch(void* const* d_in, const int* in_sizes, int n_in,
                              void* d_out, int out_size, void* d_ws, size_t ws_size,
                              hipStream_t stream) {
    const float* emb  = (const float*)d_in[0];
    const int* labels = (const int*)d_in[1];
    float* out        = (float*)d_out;
    char* ws          = (char*)d_ws;

    unsigned char* ebf = (unsigned char*)(ws + EBF_OFF);
    float* enorm       = (float*)(ws + ENORM_OFF);
    int*   cnt         = (int*)(ws + CNT_OFF);
    float* z           = (float*)(ws + Z_OFF);
    int*   rowlist     = (int*)(ws + RL_OFF);
    float* S           = (float*)(ws + S_OFF);

    hipMemsetAsync(ws + CNT_OFF, 0, ZERO_SZ, stream);

    prep_kernel<<<N / 8, 256, 0, stream>>>(emb, labels, ebf, cnt, enorm, rowlist, z);
    zsum_kernel<<<dim3(XGRID, YGRID), 256, 0, stream>>>(ebf, z, enorm, cnt, rowlist, S);
    final_kernel<<<1, 1024, 0, stream>>>(labels, cnt, z, S, out);
}

// Round 12
// 116.050 us; speedup vs baseline: 1.7952x; 1.0774x over previous
//
#include <hip/hip_runtime.h>

// ContrastiveLoss on MI355X (gfx950) — round 16
// loss = (1/n) [ sum_i P_i*(10+ln z_i) - 10*(sum_c ||S_c||^2 - n) ]
//   z_i = sum_{j != i} exp(10*dot_ij - 10)
// R16: DISAMBIGUATION — zsum/prep/final math reverted to byte-exact R12
// semantics (the 115.9us best: unscaled bf16 E, fmaf+exp2, SCALAR
// zacc/ctot epilogue). R13's SQK-prescale + f32x4 epilogue is the prime
// suspect for the +9us (likely VGPR growth past the 128/4-wave cliff:
// R9's zsum was 116, only 12 below; stagger was proven ~neutral by R15).
// Kept (independent, clean): prep zeroes z slab; memset 512B only.
// If this re-measures ~125, R12's 115.9 was noise and we are at the
// fill-dominated plateau.

#define N 8192
#define D 128
#define NCLS 100
#define NTILE 512          // N/16 tiles
#define RLCAP 256          // rowlist slots per class (~82+-9 expected)
#define MWIN 8             // m-values per window
#define YGRID 32           // m-windows: covers m = 1..256 (+extras 257..259)
#define XGRID 36           // 32 zsum i-blocks + 4 cols of classsum blocks
#define LDS_TILES 20       // rel = w*4 (<=12) + (m-m_lo) (<=7)
#define K2E 14.4269504088896340736f   // 10*log2(e)
#define LN2 0.69314718055994530942f

typedef __bf16 bf16x8 __attribute__((ext_vector_type(8)));
typedef float f32x4 __attribute__((ext_vector_type(4)));

// ws layout (bytes)
#define EBF_OFF  0x000000u  // bf16 E fragment-major: 2 MB
#define ENORM_OFF 0x200000u // fp32 normalized E row-major: 4 MB
#define CNT_OFF  0x600000u  // class counts: 512 B (zeroed)
#define Z_OFF    0x600200u  // z per row: 32 KB (zeroed by prep)
#define RL_OFF   0x608200u  // rowlist: 100*256*4 = 100 KB (gated by cnt)
#define S_OFF    0x621200u  // S_c: 100*128*4 = 50 KB (fully written)
#define ZERO_SZ  512u

__device__ __forceinline__ unsigned short f32_to_bf16_rne(float f) {
    unsigned int u = __float_as_uint(f);
    u += 0x7fffu + ((u >> 16) & 1u);
    return (unsigned short)(u >> 16);
}

// Fragment-major layout of E (harness-verified):
//   row r: grp=r>>4, col=r&15 ; element k: c=k>>5, q=(k>>3)&3, jj=k&7
//   byte = grp*4096 + c*1024 + q*256 + col*16 + jj*2
// float4 lane mapping: lane li in [0,32) holds k=4li..4li+3 ->
//   c=li>>3, q=(li>>1)&3, byte base + (li&1)*8, one 8B store.

// Kernel 1: normalize rows -> fragment-major bf16 E + row-major fp32 enorm;
// class histogram doubles as rowlist slot allocator; zeroes the z slab.
__global__ __launch_bounds__(256) void prep_kernel(
        const float* __restrict__ emb, const int* __restrict__ labels,
        unsigned char* __restrict__ ebf, int* __restrict__ cnt,
        float* __restrict__ enorm, int* __restrict__ rowlist,
        float* __restrict__ z) {
    const int w    = threadIdx.x >> 6;
    const int lane = threadIdx.x & 63;
    const int h    = lane >> 5;
    const int li   = lane & 31;
    const int row  = blockIdx.x * 8 + w * 2 + h;

    if (threadIdx.x < 8) z[blockIdx.x * 8 + threadIdx.x] = 0.0f;

    const float4 v = *(const float4*)(emb + (size_t)row * D + li * 4);
    float ss = v.x * v.x + v.y * v.y + v.z * v.z + v.w * v.w;
    #pragma unroll
    for (int off = 16; off; off >>= 1) ss += __shfl_xor(ss, off);   // within half
    const float inv = 1.0f / fmaxf(sqrtf(ss), 1e-12f);
    const float e0 = v.x * inv, e1 = v.y * inv, e2 = v.z * inv, e3 = v.w * inv;

    const int grp = row >> 4, col = row & 15;
    const int c = li >> 3, q = (li >> 1) & 3, jh = li & 1;
    uint2 packed;
    packed.x = (unsigned)f32_to_bf16_rne(e0) | ((unsigned)f32_to_bf16_rne(e1) << 16);
    packed.y = (unsigned)f32_to_bf16_rne(e2) | ((unsigned)f32_to_bf16_rne(e3) << 16);
    *(uint2*)(ebf + grp * 4096 + c * 1024 + q * 256 + col * 16 + jh * 8) = packed;

    *(float4*)(enorm + (size_t)row * D + li * 4) = make_float4(e0, e1, e2, e3);

    if (li == 0) {
        const int lab = labels[row];
        int slot = atomicAdd(&cnt[lab], 1);
        slot = slot < RLCAP ? slot : RLCAP - 1;   // defensive
        rowlist[lab * RLCAP + slot] = row;
    }
}

// Kernel 2: zsum (blocks x<32) + classsum (blocks x>=32, 1 class each).
// zsum: circulant symmetry — wave owns 4 consecutive i-tiles; window y
// handles m in [8y+1, 8y+8] (+1 extra for y in {29,30,31}); monotone
// m-walk. Group g active iff d=m-g in [1,255], or d==256 for low-half
// blocks. Diagonal tiles: window 0, row-sums with self-exclusion.
// Off-diag credit BOTH sides: rows in registers, cols via LDS partials.
__global__ __launch_bounds__(256) void zsum_kernel(
        const unsigned char* __restrict__ ebf, float* __restrict__ z,
        const float* __restrict__ enorm, const int* __restrict__ cnt,
        const int* __restrict__ rowlist, float* __restrict__ S) {
    const int t = threadIdx.x;

    if (blockIdx.x >= 32) {
        // ---- classsum path: exact fp32 per-class sums via rowlist gather ----
        const int eidx = (blockIdx.x - 32) * YGRID + blockIdx.y;
        if (eidx >= NCLS || t >= 128) return;
        const int d = t;
        const int n = cnt[eidx] < RLCAP ? cnt[eidx] : RLCAP;
        const int* rl = rowlist + eidx * RLCAP;
        float acc = 0.0f;
        int idx = 0;
        for (; idx + 4 <= n; idx += 4) {
            const int r0 = rl[idx], r1 = rl[idx + 1], r2 = rl[idx + 2], r3 = rl[idx + 3];
            acc += enorm[(size_t)r0 * D + d] + enorm[(size_t)r1 * D + d]
                 + enorm[(size_t)r2 * D + d] + enorm[(size_t)r3 * D + d];
        }
        for (; idx < n; ++idx)
            acc += enorm[(size_t)rl[idx] * D + d];
        S[eidx * D + d] = acc;
        return;
    }

    // ---- zsum path ----
    __shared__ float zcol[LDS_TILES * 16];
    const int w    = t >> 6;
    const int lane = t & 63;
    const int q    = lane >> 4;
    const int col  = lane & 15;
    const int bi   = blockIdx.x;                 // 0..31  i-block
    const int y    = blockIdx.y;                 // 0..31  m-window
    const int ti0  = bi * 16 + w * 4;            // wave's first i-tile
    const int m_lo = y * MWIN + 1;
    const bool lowhalf = (bi < 16);

    for (int e = t; e < LDS_TILES * 16; e += 256) zcol[e] = 0.0f;

    // A fragments: 4 i-tiles x 4 K-chunks, coalesced 1KB loads
    bf16x8 a[4][4];
    #pragma unroll
    for (int g = 0; g < 4; ++g) {
        const unsigned char* ag = ebf + (size_t)(ti0 + g) * 4096 + lane * 16;
        #pragma unroll
        for (int c = 0; c < 4; ++c) a[g][c] = *(const bf16x8*)(ag + c * 1024);
    }

    float zacc[4][4] = {{0.f,0.f,0.f,0.f},{0.f,0.f,0.f,0.f},
                        {0.f,0.f,0.f,0.f},{0.f,0.f,0.f,0.f}};

    __syncthreads();   // zcol zeroed

    // diagonal tiles: window 0 only; full tile, self excluded, row-sums only
    if (y == 0) {
        #pragma unroll
        for (int g = 0; g < 4; ++g) {
            const unsigned char* bg = ebf + (size_t)(ti0 + g) * 4096 + lane * 16;
            bf16x8 bd[4];
            #pragma unroll
            for (int c = 0; c < 4; ++c) bd[c] = *(const bf16x8*)(bg + c * 1024);
            f32x4 acc = {0.f, 0.f, 0.f, 0.f};
            #pragma unroll
            for (int c = 0; c < 4; ++c)
                acc = __builtin_amdgcn_mfma_f32_16x16x32_bf16(a[g][c], bd[c], acc, 0, 0, 0);
            #pragma unroll
            for (int r = 0; r < 4; ++r)
                zacc[g][r] += (col == q * 4 + r) ? 0.0f
                    : __builtin_amdgcn_exp2f(fmaf(acc[r], K2E, -K2E));
        }
    }

    const int ns = MWIN + ((y == 29 || y == 30 || (y == 31 && lowhalf)) ? 1 : 0);
    const int m_x = 228 + y;

    // prologue: load B tile for s=0
    bf16x8 bc[4];
    {
        const int tj = (ti0 + m_lo) & (NTILE - 1);
        const unsigned char* bg = ebf + (size_t)tj * 4096 + lane * 16;
        #pragma unroll
        for (int c = 0; c < 4; ++c) bc[c] = *(const bf16x8*)(bg + c * 1024);
    }

    #pragma unroll 2
    for (int s = 0; s < ns; ++s) {
        const int m = (s < MWIN) ? (m_lo + s) : m_x;

        // prefetch next B tile (last iter reloads current — harmless)
        const int sn = (s + 1 < ns) ? s + 1 : s;
        const int mn = (sn < MWIN) ? (m_lo + sn) : m_x;
        bf16x8 bn[4];
        {
            const int tjn = (ti0 + mn) & (NTILE - 1);
            const unsigned char* bg = ebf + (size_t)tjn * 4096 + lane * 16;
            #pragma unroll
            for (int c = 0; c < 4; ++c) bn[c] = *(const bf16x8*)(bg + c * 1024);
        }

        float ctot = 0.0f;
        #pragma unroll
        for (int g = 0; g < 4; ++g) {
            const int d = m - g;
            const bool act = (d >= 1 && d <= 255) || (d == 256 && lowhalf);
            if (act) {
                f32x4 acc = {0.f, 0.f, 0.f, 0.f};
                __builtin_amdgcn_s_setprio(1);
                #pragma unroll
                for (int c = 0; c < 4; ++c)
                    acc = __builtin_amdgcn_mfma_f32_16x16x32_bf16(a[g][c], bc[c], acc, 0, 0, 0);
                __builtin_amdgcn_s_setprio(0);
                #pragma unroll
                for (int r = 0; r < 4; ++r) {
                    const float p = __builtin_amdgcn_exp2f(fmaf(acc[r], K2E, -K2E));
                    zacc[g][r] += p;
                    ctot += p;
                }
            }
        }

        // column sums -> j-side credit. Reduce across q (rows of tile).
        ctot += __shfl_xor(ctot, 16);
        ctot += __shfl_xor(ctot, 32);
        if (q == 0 && ctot != 0.0f) {
            if (s < MWIN) {
                const int rel = w * 4 + (m - m_lo);          // 0..19
                atomicAdd(&zcol[rel * 16 + col], ctot);
            } else {
                const int tj = (ti0 + m) & (NTILE - 1);
                atomicAdd(&z[tj * 16 + col], ctot);
            }
        }

        #pragma unroll
        for (int c = 0; c < 4; ++c) bc[c] = bn[c];
    }

    // i-side: per-row reduce across the 16 cols of each quad
    #pragma unroll
    for (int g = 0; g < 4; ++g)
        #pragma unroll
        for (int r = 0; r < 4; ++r) {
            float zv = zacc[g][r];
            zv += __shfl_xor(zv, 1);
            zv += __shfl_xor(zv, 2);
            zv += __shfl_xor(zv, 4);
            zv += __shfl_xor(zv, 8);
            if (col == 0)
                atomicAdd(&z[(ti0 + g) * 16 + q * 4 + r], zv);
        }

    // j-side: flush LDS col-partials once
    __syncthreads();
    for (int e = t; e < LDS_TILES * 16; e += 256) {
        const float v = zcol[e];
        if (v != 0.0f) {
            const int tj = (bi * 16 + m_lo + (e >> 4)) & (NTILE - 1);
            atomicAdd(&z[tj * 16 + (e & 15)], v);
        }
    }
}

// Kernel 3: single-block epilogue.
// loss = [ sum_i P_i*(10+ln z_i) - 10*sum_k S[k]^2 + 10*N ] / N
__global__ __launch_bounds__(1024) void final_kernel(
        const int* __restrict__ labels, const int* __restrict__ cnt,
        const float* __restrict__ z, const float* __restrict__ S,
        float* __restrict__ out) {
    __shared__ float part[16];
    const int tid = threadIdx.x;
    float acc = 0.0f;
    #pragma unroll
    for (int k = 0; k < N / 1024; ++k) {
        const int row = k * 1024 + tid;
        const int P = cnt[labels[row]] - 1;
        if (P > 0)
            acc += (float)P * fmaf(LN2, __builtin_amdgcn_logf(z[row]), 10.0f);
    }
    #pragma unroll
    for (int k = 0; k < (NCLS * D + 1023) / 1024; ++k) {
        const int idx = k * 1024 + tid;
        if (idx < NCLS * D) {
            const float sv = S[idx];
            acc -= 10.0f * sv * sv;
        }
    }
    #pragma unroll
    for (int off = 32; off; off >>= 1) acc += __shfl_xor(acc, off);
    if ((tid & 63) == 0) part[tid >> 6] = acc;
    __syncthreads();
    if (tid == 0) {
        float tot = 0.0f;
        #pragma unroll
        for (int w = 0; w < 16; ++w) tot += part[w];
        out[0] = (tot + 10.0f * (float)N) * (1.0f / (float)N);
    }
}

extern "C" void kernel_launch(void* const* d_in, const int* in_sizes, int n_in,
                              void* d_out, int out_size, void* d_ws, size_t ws_size,
                              hipStream_t stream) {
    const float* emb  = (const float*)d_in[0];
    const int* labels = (const int*)d_in[1];
    float* out        = (float*)d_out;
    char* ws          = (char*)d_ws;

    unsigned char* ebf = (unsigned char*)(ws + EBF_OFF);
    float* enorm       = (float*)(ws + ENORM_OFF);
    int*   cnt         = (int*)(ws + CNT_OFF);
    float* z           = (float*)(ws + Z_OFF);
    int*   rowlist     = (int*)(ws + RL_OFF);
    float* S           = (float*)(ws + S_OFF);

    hipMemsetAsync(ws + CNT_OFF, 0, ZERO_SZ, stream);

    prep_kernel<<<N / 8, 256, 0, stream>>>(emb, labels, ebf, cnt, enorm, rowlist, z);
    zsum_kernel<<<dim3(XGRID, YGRID), 256, 0, stream>>>(ebf, z, enorm, cnt, rowlist, S);
    final_kernel<<<1, 1024, 0, stream>>>(labels, cnt, z, S, out);
}